// Round 8
// baseline (100.958 us; speedup 1.0000x reference)
//
#include <hip/hip_runtime.h>
#include <hip/hip_bf16.h>

typedef short bf16x8 __attribute__((ext_vector_type(8)));
typedef float f32x4 __attribute__((ext_vector_type(4)));
typedef _Float16 half4 __attribute__((ext_vector_type(4)));

__device__ __forceinline__ short f2bf(float f) {
    union { float f; unsigned u; } v; v.f = f;
    unsigned r = (v.u + 0x7FFFu + ((v.u >> 16) & 1u)) >> 16;
    return (short)r;
}

__device__ __forceinline__ float selu_f(float x) {
    const float scale = 1.0507009873554805f;
    const float sa = 1.0507009873554805f * 1.6732632423543772f;
    return x > 0.f ? scale * x : sa * (__expf(x) - 1.f);
}

__device__ __forceinline__ void gld_lds16(const char* g, char* l) {
    __builtin_amdgcn_global_load_lds(
        (const __attribute__((address_space(1))) unsigned int*)g,
        (__attribute__((address_space(3))) unsigned int*)l, 16, 0, 0);
}

// ---------------------------------------------------------------------------
// Kernel 1 (merged prep): blocks 0-511: cbias; 512-767: w1img; 768-783: wvec
// ---------------------------------------------------------------------------
__global__ void __launch_bounds__(512) prep_all_kernel(
    const float* __restrict__ c, const int* __restrict__ lat_idx,
    const int* __restrict__ lon_idx,
    const float* __restrict__ f2W1, const float* __restrict__ f2b1,
    const float* __restrict__ f2W2, const float* __restrict__ f2b2,
    const float* __restrict__ fW1, const float* __restrict__ fb1,
    const float* __restrict__ fW21, const float* __restrict__ fW22,
    short* __restrict__ w1img, _Float16* __restrict__ wvec,
    float* __restrict__ cbias)
{
    const int bid = blockIdx.x;
    const int t = threadIdx.x;

    if (bid < 512) {
        __shared__ int cells[64];
        __shared__ float ctraj[128];
        __shared__ float hbuf[256];
        __shared__ float ctrf[128];
        const int b = bid;

        if (t < 64) cells[t] = lat_idx[b * 64 + t] * 17 + lon_idx[b * 64 + t];
        __syncthreads();

        if (t < 128) {
            float s = 0.f;
            #pragma unroll 8
            for (int j = 0; j < 64; ++j) s += c[t * 289 + cells[j]];
            ctraj[t] = s * (1.f / 64.f);
        }
        __syncthreads();

        if (t < 256) {
            float acc = f2b1[t];
            #pragma unroll 8
            for (int i = 0; i < 128; ++i) acc += ctraj[i] * f2W1[i * 256 + t];
            hbuf[t] = selu_f(acc);
        }
        __syncthreads();

        if (t < 128) {
            float acc = f2b2[t];
            #pragma unroll 8
            for (int i = 0; i < 256; ++i) acc += hbuf[i] * f2W2[i * 128 + t];
            ctrf[t] = acc;
        }
        __syncthreads();

        float acc = fb1[t];
        #pragma unroll 8
        for (int i = 0; i < 128; ++i) acc += ctrf[i] * fW1[(256 + i) * 512 + t];
        cbias[b * 512 + t] = acc;
    } else if (bid < 768) {
        int I = (bid - 512) * 512 + t;        // 0..131071
        int e = I & 7;
        int lane = (I >> 3) & 63;
        int cg = (I >> 9) & 31;
        int kc = I >> 14;
        int col = cg * 16 + (lane & 15);
        int k = kc * 32 + ((lane >> 4) << 3) + e;
        w1img[I] = f2bf(fW1[k * 512 + col]);
    } else {
        int I = (bid - 768) * 512 + t;        // 0..8191
        int e = I & 3;
        int lane = (I >> 2) & 63;
        int nc = I >> 8;
        int l15 = lane & 15, hi = lane >> 4;
        int n = nc * 16 + hi * 4 + e;
        float v = (l15 == 0) ? fW21[n] : (l15 == 1 ? fW22[n] : 0.f);
        wvec[I] = (_Float16)v;
    }
}

// ---------------------------------------------------------------------------
// Kernel 2: fused GEMM (K=256) + selu + MFMA reduce, n-split partials.
// 2048 blocks (b x s-half x n-half) x 512 threads (8 waves, 2x4 of 64x64).
// LDS 52KB: A dbuf 2x8K @0 | B dbuf 2x16K @16384 | redM @49152 | redV @51200
// Counted vmcnt: drain exactly B(I) before MFMA(I); prefetch stays in flight.
// ---------------------------------------------------------------------------
__global__ void __launch_bounds__(512, 4) fused_gemm_kernel(
    const float* __restrict__ rho, const short* __restrict__ w1img,
    const float* __restrict__ cbias, const _Float16* __restrict__ wvec,
    float* __restrict__ plmP, float* __restrict__ plvP)
{
    __shared__ __align__(16) char smem[53248];

    const int tid  = threadIdx.x;
    const int lane = tid & 63;
    const int wid  = tid >> 6;     // 0..7
    const int wr   = wid >> 2;     // 0..1 row-group
    const int wc   = wid & 3;      // 0..3 col-group
    const int l15  = lane & 15;
    const int hi   = lane >> 4;

    const int b  = blockIdx.x >> 2;
    const int s0 = ((blockIdx.x >> 1) & 1) << 7;
    const int nh = blockIdx.x & 1;

    // A staging: thread t covers row (t>>6)*16 + (t&15), k-octet (t&63)>>4
    const float* prA = rho + (size_t)(b * 256 + s0 + (tid >> 6) * 16 + (tid & 15)) * 256
                           + (((tid & 63) >> 4) << 3);
    char* aw = smem + tid * 16;

    // B staging: wave stages local col-groups wid*2, wid*2+1 (of 16)
    const char* wsrc = (const char*)w1img
                     + ((size_t)(nh * 16 + wid * 2) * 64 + lane) * 16;
    char* bw = smem + 16384 + (wid * 2) * 1024;

    f32x4 acc[4][4];   // [nf][sf]: col-frag x row-frag (C^T layout, swapped ops)
    #pragma unroll
    for (int nf = 0; nf < 4; ++nf)
        #pragma unroll
        for (int sf = 0; sf < 4; ++sf)
            acc[nf][sf] = (f32x4){0.f, 0.f, 0.f, 0.f};

    float4 e0, e1, o0, o1;

    // ---- prologue: A(0) loads first (so cvt's implicit wait keeps B in flight)
    e0 = *(const float4*)(prA);
    e1 = *(const float4*)(prA + 4);
    gld_lds16(wsrc, smem + 16384 + (wid * 2) * 1024);
    gld_lds16(wsrc + 1024, smem + 16384 + (wid * 2) * 1024 + 1024);

#define CHUNK(I, C0, C1, N0, N1, LAST)                                         \
    {                                                                          \
        bf16x8 hh;                                                             \
        hh[0]=f2bf(C0.x); hh[1]=f2bf(C0.y); hh[2]=f2bf(C0.z); hh[3]=f2bf(C0.w);\
        hh[4]=f2bf(C1.x); hh[5]=f2bf(C1.y); hh[6]=f2bf(C1.z); hh[7]=f2bf(C1.w);\
        *(bf16x8*)(aw + ((I)&1) * 8192) = hh;                                  \
        if (!(LAST)) {                                                         \
            N0 = *(const float4*)(prA + ((I)+1) * 32);                         \
            N1 = *(const float4*)(prA + ((I)+1) * 32 + 4);                     \
            gld_lds16(wsrc + ((I)+1) * 32768,                                  \
                      bw + (((I)+1)&1) * 16384);                               \
            gld_lds16(wsrc + ((I)+1) * 32768 + 1024,                           \
                      bw + (((I)+1)&1) * 16384 + 1024);                        \
        }                                                                      \
        asm volatile("s_waitcnt lgkmcnt(0)" ::: "memory");                     \
        if (LAST) asm volatile("s_waitcnt vmcnt(0)" ::: "memory");             \
        else      asm volatile("s_waitcnt vmcnt(4)" ::: "memory");             \
        __builtin_amdgcn_s_barrier();                                          \
        __builtin_amdgcn_sched_barrier(0);                                     \
        {                                                                      \
            bf16x8 aF[4], bF[4];                                               \
            const char* ab = smem + ((I)&1) * 8192;                            \
            const char* bb = smem + 16384 + ((I)&1) * 16384;                   \
            _Pragma("unroll")                                                  \
            for (int sf = 0; sf < 4; ++sf)                                     \
                aF[sf] = *(const bf16x8*)(ab + (((wr*4+sf)*64 + lane) << 4));  \
            _Pragma("unroll")                                                  \
            for (int nf = 0; nf < 4; ++nf)                                     \
                bF[nf] = *(const bf16x8*)(bb + (((wc*4+nf)*64 + lane) << 4));  \
            __builtin_amdgcn_s_setprio(1);                                     \
            _Pragma("unroll")                                                  \
            for (int nf = 0; nf < 4; ++nf)                                     \
                _Pragma("unroll")                                              \
                for (int sf = 0; sf < 4; ++sf)                                 \
                    acc[nf][sf] = __builtin_amdgcn_mfma_f32_16x16x32_bf16(     \
                        bF[nf], aF[sf], acc[nf][sf], 0, 0, 0);                 \
            __builtin_amdgcn_s_setprio(0);                                     \
        }                                                                      \
        __builtin_amdgcn_sched_barrier(0);                                     \
        __builtin_amdgcn_s_barrier();                                          \
    }

    CHUNK(0, e0, e1, o0, o1, false)
    CHUNK(1, o0, o1, e0, e1, false)
    CHUNK(2, e0, e1, o0, o1, false)
    CHUNK(3, o0, o1, e0, e1, false)
    CHUNK(4, e0, e1, o0, o1, false)
    CHUNK(5, o0, o1, e0, e1, false)
    CHUNK(6, e0, e1, o0, o1, false)
    CHUNK(7, o0, o1, e0, e1, true)
#undef CHUNK

    // ---- epilogue: selu(acc + cbias) -> f16 frags -> 16x16x16 reduce MFMA ----
    f32x4 rd[4];
    #pragma unroll
    for (int sf = 0; sf < 4; ++sf) rd[sf] = (f32x4){0.f, 0.f, 0.f, 0.f};

    #pragma unroll
    for (int nf = 0; nf < 4; ++nf) {
        int nc = nh * 16 + wc * 4 + nf;               // global 16-col chunk
        f32x4 cbf = *(const f32x4*)(cbias + b * 512 + nc * 16 + hi * 4);
        half4 wv = *(const half4*)(wvec + (size_t)nc * 256 + lane * 4);
        #pragma unroll
        for (int sf = 0; sf < 4; ++sf) {
            half4 pa;
            #pragma unroll
            for (int q = 0; q < 4; ++q)
                pa[q] = (_Float16)selu_f(acc[nf][sf][q] + cbf[q]);
            rd[sf] = __builtin_amdgcn_mfma_f32_16x16x16f16(pa, wv, rd[sf], 0, 0, 0);
        }
    }

    float* redM = (float*)(smem + 49152);   // [4][128]
    float* redV = (float*)(smem + 51200);   // [4][128]
    if (l15 == 0) {
        #pragma unroll
        for (int sf = 0; sf < 4; ++sf)
            *(f32x4*)&redM[wc * 128 + wr * 64 + sf * 16 + hi * 4] = rd[sf];
    } else if (l15 == 1) {
        #pragma unroll
        for (int sf = 0; sf < 4; ++sf)
            *(f32x4*)&redV[wc * 128 + wr * 64 + sf * 16 + hi * 4] = rd[sf];
    }

    __syncthreads();
    size_t obase = (size_t)nh * 131072 + (size_t)b * 256 + s0;
    if (tid < 128) {
        plmP[obase + tid] = redM[tid] + redM[128 + tid] + redM[256 + tid] + redM[384 + tid];
    } else if (tid < 256) {
        int rr = tid - 128;
        plvP[obase + rr] = redV[rr] + redV[128 + rr] + redV[256 + rr] + redV[384 + rr];
    }
}

// ---------------------------------------------------------------------------
// Kernel 3: per-b logsumexp over S=256 (summing n-half partials) + outputs
// ---------------------------------------------------------------------------
__global__ void __launch_bounds__(64) finalize_kernel(
    const float* __restrict__ plmP, const float* __restrict__ plvP,
    const float* __restrict__ w, const float* __restrict__ l,
    const float* __restrict__ b21p, const float* __restrict__ b22p,
    float* __restrict__ out)
{
    const int b = blockIdx.x;
    const int lane = threadIdx.x;
    const float b21 = b21p[0], b22 = b22p[0];

    float a1[4], a2[4];
    float m1 = -1e30f, m2 = -1e30f;
    #pragma unroll
    for (int i = 0; i < 4; ++i) {
        int s = i * 64 + lane;
        int idx = b * 256 + s;
        float lw = logf(w[idx]);
        a1[i] = plmP[idx] + plmP[131072 + idx] + b21 + lw;
        a2[i] = plvP[idx] + plvP[131072 + idx] + b22 + 2.f * lw;
        m1 = fmaxf(m1, a1[i]);
        m2 = fmaxf(m2, a2[i]);
    }
    #pragma unroll
    for (int m = 1; m < 64; m <<= 1) {
        m1 = fmaxf(m1, __shfl_xor(m1, m));
        m2 = fmaxf(m2, __shfl_xor(m2, m));
    }
    float s1 = 0.f, s2 = 0.f;
    #pragma unroll
    for (int i = 0; i < 4; ++i) {
        s1 += expf(a1[i] - m1);
        s2 += expf(a2[i] - m2);
    }
    #pragma unroll
    for (int m = 1; m < 64; m <<= 1) {
        s1 += __shfl_xor(s1, m);
        s2 += __shfl_xor(s2, m);
    }
    if (lane == 0) {
        float lm_agg = m1 + logf(s1);
        float lv_agg = m2 + logf(s2);
        float logl = logf(l[b]);
        out[b]       = logl - lm_agg;
        out[512 + b] = logl - 3.f * lm_agg - lv_agg;
    }
}

extern "C" void kernel_launch(void* const* d_in, const int* in_sizes, int n_in,
                              void* d_out, int out_size, void* d_ws, size_t ws_size,
                              hipStream_t stream) {
    const float* rho     = (const float*)d_in[0];
    const float* c       = (const float*)d_in[1];
    const float* w       = (const float*)d_in[2];
    const float* l       = (const float*)d_in[3];
    // d_in[4] = roads (unused by the reference)
    const int*   lon_idx = (const int*)d_in[5];
    const int*   lat_idx = (const int*)d_in[6];
    const float* f2W1    = (const float*)d_in[7];
    const float* f2b1    = (const float*)d_in[8];
    const float* f2W2    = (const float*)d_in[9];
    const float* f2b2    = (const float*)d_in[10];
    const float* fW1     = (const float*)d_in[11];
    const float* fb1     = (const float*)d_in[12];
    const float* fW21    = (const float*)d_in[13];
    const float* fb21    = (const float*)d_in[14];
    const float* fW22    = (const float*)d_in[15];
    const float* fb22    = (const float*)d_in[16];
    float* out = (float*)d_out;

    char* ws = (char*)d_ws;
    float*     cbias = (float*)(ws);               // 1048576 B
    short*     w1img = (short*)(ws + 1048576);     //  262144 B
    float*     plmP  = (float*)(ws + 1310720);     // 1048576 B (2 halves)
    float*     plvP  = (float*)(ws + 2359296);     // 1048576 B (2 halves)
    _Float16*  wvec  = (_Float16*)(ws + 3407872);  //   16384 B

    prep_all_kernel<<<784, 512, 0, stream>>>(c, lat_idx, lon_idx,
                                             f2W1, f2b1, f2W2, f2b2,
                                             fW1, fb1, fW21, fW22,
                                             w1img, wvec, cbias);
    fused_gemm_kernel<<<2048, 512, 0, stream>>>(rho, w1img, cbias, wvec,
                                                plmP, plvP);
    finalize_kernel<<<512, 64, 0, stream>>>(plmP, plvP, w, l, fb21, fb22, out);
}

// Round 9
// 92.334 us; speedup vs baseline: 1.0934x; 1.0934x over previous
//
#include <hip/hip_runtime.h>
#include <hip/hip_bf16.h>

typedef short bf16x8 __attribute__((ext_vector_type(8)));
typedef float f32x4 __attribute__((ext_vector_type(4)));
typedef _Float16 half4 __attribute__((ext_vector_type(4)));

__device__ __forceinline__ short f2bf(float f) {
    union { float f; unsigned u; } v; v.f = f;
    unsigned r = (v.u + 0x7FFFu + ((v.u >> 16) & 1u)) >> 16;
    return (short)r;
}

__device__ __forceinline__ float selu_f(float x) {
    const float scale = 1.0507009873554805f;
    const float sa = 1.0507009873554805f * 1.6732632423543772f;
    return x > 0.f ? scale * x : sa * (__expf(x) - 1.f);
}

// ---------------------------------------------------------------------------
// Kernel 1 (merged prep): blocks 0-511: cbias; 512-767: w1img; 768-783: wvec
// ---------------------------------------------------------------------------
__global__ void __launch_bounds__(512) prep_all_kernel(
    const float* __restrict__ c, const int* __restrict__ lat_idx,
    const int* __restrict__ lon_idx,
    const float* __restrict__ f2W1, const float* __restrict__ f2b1,
    const float* __restrict__ f2W2, const float* __restrict__ f2b2,
    const float* __restrict__ fW1, const float* __restrict__ fb1,
    const float* __restrict__ fW21, const float* __restrict__ fW22,
    short* __restrict__ w1img, _Float16* __restrict__ wvec,
    float* __restrict__ cbias)
{
    const int bid = blockIdx.x;
    const int t = threadIdx.x;

    if (bid < 512) {
        __shared__ int cells[64];
        __shared__ float ctraj[128];
        __shared__ float hbuf[256];
        __shared__ float ctrf[128];
        const int b = bid;

        if (t < 64) cells[t] = lat_idx[b * 64 + t] * 17 + lon_idx[b * 64 + t];
        __syncthreads();

        if (t < 128) {
            float s = 0.f;
            #pragma unroll 8
            for (int j = 0; j < 64; ++j) s += c[t * 289 + cells[j]];
            ctraj[t] = s * (1.f / 64.f);
        }
        __syncthreads();

        if (t < 256) {
            float acc = f2b1[t];
            #pragma unroll 8
            for (int i = 0; i < 128; ++i) acc += ctraj[i] * f2W1[i * 256 + t];
            hbuf[t] = selu_f(acc);
        }
        __syncthreads();

        if (t < 128) {
            float acc = f2b2[t];
            #pragma unroll 8
            for (int i = 0; i < 256; ++i) acc += hbuf[i] * f2W2[i * 128 + t];
            ctrf[t] = acc;
        }
        __syncthreads();

        float acc = fb1[t];
        #pragma unroll 8
        for (int i = 0; i < 128; ++i) acc += ctrf[i] * fW1[(256 + i) * 512 + t];
        cbias[b * 512 + t] = acc;
    } else if (bid < 768) {
        int I = (bid - 512) * 512 + t;        // 0..131071
        int e = I & 7;
        int lane = (I >> 3) & 63;
        int cg = (I >> 9) & 31;
        int kc = I >> 14;
        int col = cg * 16 + (lane & 15);
        int k = kc * 32 + ((lane >> 4) << 3) + e;
        w1img[I] = f2bf(fW1[k * 512 + col]);
    } else {
        int I = (bid - 768) * 512 + t;        // 0..8191
        int e = I & 3;
        int lane = (I >> 2) & 63;
        int nc = I >> 8;
        int l15 = lane & 15, hi = lane >> 4;
        int n = nc * 16 + hi * 4 + e;
        float v = (l15 == 0) ? fW21[n] : (l15 == 1 ? fW22[n] : 0.f);
        wvec[I] = (_Float16)v;
    }
}

// ---------------------------------------------------------------------------
// Kernel 2: fused GEMM (K=256) + selu + MFMA reduce.
// 2048 blocks (b x s-quarter) x 512 threads (8 waves, each 64 rows x 64 cols
// of the 64x512 block tile; all waves share the A rows).
// A: staged ONCE, fully-coalesced global reads (32B/lane contiguous) ->
//    cvt_pk -> XOR-swizzled fragment-major LDS (conflict-free both sides).
// B: per-wave global reg-dbuf from L2-resident fragment-major image.
// Zero barriers in the K-loop. R6 MFMA-reduce epilogue.
// ---------------------------------------------------------------------------
__global__ void __launch_bounds__(512, 4) fused_gemm_kernel(
    const float* __restrict__ rho, const short* __restrict__ w1img,
    const float* __restrict__ cbias, const _Float16* __restrict__ wvec,
    float* __restrict__ plm, float* __restrict__ plv)
{
    __shared__ __align__(16) char smA[36864];   // A 32KB | redM 2KB | redV 2KB

    const int tid  = threadIdx.x;
    const int lane = tid & 63;
    const int w    = tid >> 6;      // 0..7
    const int l15  = lane & 15;
    const int hi   = lane >> 4;     // 0..3

    const int b  = blockIdx.x >> 2;
    const int s0 = (blockIdx.x & 3) << 6;

    // ---- stage A once: coalesced reads, swizzled fragment-major writes ----
    // thread t, iter j: floats [j*4096 + t*8, +8) of the 64x256 f32 tile
    //   row = j*16 + (t>>5), k = (t&31)*8 + e
    //   frag slot: kc=(t>>2)&7, hi_w=t&3, rg=j, l15row=t>>5
    //   swizzle: store l15row at (l15row ^ ((kc&3)<<2|hi_w)) = l15row ^ (t&15)
    {
        const float* src = rho + (size_t)(b * 256 + s0) * 256 + tid * 8;
        const int kc_w = (tid >> 2) & 7;
        const int hi_w = tid & 3;
        const int sw_w = (tid >> 5) ^ (tid & 15);
        #pragma unroll
        for (int j = 0; j < 4; ++j) {
            float4 f0 = *(const float4*)(src + j * 4096);
            float4 f1 = *(const float4*)(src + j * 4096 + 4);
            union { bf16x8 h; unsigned u[4]; } pk;
            asm("v_cvt_pk_bf16_f32 %0, %1, %2" : "=v"(pk.u[0]) : "v"(f0.x), "v"(f0.y));
            asm("v_cvt_pk_bf16_f32 %0, %1, %2" : "=v"(pk.u[1]) : "v"(f0.z), "v"(f0.w));
            asm("v_cvt_pk_bf16_f32 %0, %1, %2" : "=v"(pk.u[2]) : "v"(f1.x), "v"(f1.y));
            asm("v_cvt_pk_bf16_f32 %0, %1, %2" : "=v"(pk.u[3]) : "v"(f1.z), "v"(f1.w));
            int slot = (kc_w * 4 + j) * 64 + hi_w * 16 + sw_w;
            *(bf16x8*)(smA + (slot << 4)) = pk.h;
        }
    }
    __syncthreads();   // only block-wide barrier before the epilogue

    f32x4 acc[4][4];   // [nf][sf]: C^T (swapped ops): col-field = s, row = n
    #pragma unroll
    for (int nf = 0; nf < 4; ++nf)
        #pragma unroll
        for (int sf = 0; sf < 4; ++sf)
            acc[nf][sf] = (f32x4){0.f, 0.f, 0.f, 0.f};

    // wave w owns cols w*64..w*64+63: col-groups cg = kc*32 + w*4 + nf
    const char* bp = (const char*)w1img + w * 4096 + lane * 16;

    bf16x8 bN[4];
    #pragma unroll
    for (int nf = 0; nf < 4; ++nf)
        bN[nf] = *(const bf16x8*)(bp + nf * 1024);

    #pragma unroll
    for (int kc = 0; kc < 8; ++kc) {
        bf16x8 bC[4];
        #pragma unroll
        for (int nf = 0; nf < 4; ++nf) bC[nf] = bN[nf];
        if (kc < 7) {
            #pragma unroll
            for (int nf = 0; nf < 4; ++nf)
                bN[nf] = *(const bf16x8*)(bp + (size_t)(kc + 1) * 32768 + nf * 1024);
        }
        // swizzled A-fragment reads (perfectly conflict-free)
        const int sw_r = l15 ^ (((kc & 3) << 2) | hi);
        const char* ab = smA + ((kc * 256 + hi * 16 + sw_r) << 4);
        bf16x8 aF[4];
        #pragma unroll
        for (int sf = 0; sf < 4; ++sf)
            aF[sf] = *(const bf16x8*)(ab + sf * 1024);
        #pragma unroll
        for (int nf = 0; nf < 4; ++nf)
            #pragma unroll
            for (int sf = 0; sf < 4; ++sf)
                acc[nf][sf] = __builtin_amdgcn_mfma_f32_16x16x32_bf16(
                    bC[nf], aF[sf], acc[nf][sf], 0, 0, 0);
    }

    // ---- epilogue: selu(acc + cbias) -> f16 frags -> 16x16x16 reduce MFMA ----
    f32x4 rd[4];
    #pragma unroll
    for (int sf = 0; sf < 4; ++sf) rd[sf] = (f32x4){0.f, 0.f, 0.f, 0.f};

    #pragma unroll
    for (int nf = 0; nf < 4; ++nf) {
        f32x4 cbf = *(const f32x4*)(cbias + b * 512 + w * 64 + nf * 16 + hi * 4);
        half4 wv = *(const half4*)(wvec + (size_t)(w * 4 + nf) * 256 + lane * 4);
        #pragma unroll
        for (int sf = 0; sf < 4; ++sf) {
            half4 pa;
            #pragma unroll
            for (int q = 0; q < 4; ++q)
                pa[q] = (_Float16)selu_f(acc[nf][sf][q] + cbf[q]);
            rd[sf] = __builtin_amdgcn_mfma_f32_16x16x16f16(pa, wv, rd[sf], 0, 0, 0);
        }
    }

    float* redM = (float*)(smA + 32768);   // [8][64]
    float* redV = (float*)(smA + 34816);   // [8][64]
    if (l15 == 0) {
        #pragma unroll
        for (int sf = 0; sf < 4; ++sf)
            *(f32x4*)&redM[w * 64 + sf * 16 + hi * 4] = rd[sf];
    } else if (l15 == 1) {
        #pragma unroll
        for (int sf = 0; sf < 4; ++sf)
            *(f32x4*)&redV[w * 64 + sf * 16 + hi * 4] = rd[sf];
    }

    __syncthreads();
    size_t obase = (size_t)b * 256 + s0;
    if (tid < 64) {
        float s = 0.f;
        #pragma unroll
        for (int j = 0; j < 8; ++j) s += redM[j * 64 + tid];
        plm[obase + tid] = s;
    } else if (tid < 128) {
        int rr = tid - 64;
        float s = 0.f;
        #pragma unroll
        for (int j = 0; j < 8; ++j) s += redV[j * 64 + rr];
        plv[obase + rr] = s;
    }
}

// ---------------------------------------------------------------------------
// Kernel 3: per-b logsumexp over S=256 and final outputs (1 wave per b)
// ---------------------------------------------------------------------------
__global__ void __launch_bounds__(64) finalize_kernel(
    const float* __restrict__ plm, const float* __restrict__ plv,
    const float* __restrict__ w, const float* __restrict__ l,
    const float* __restrict__ b21p, const float* __restrict__ b22p,
    float* __restrict__ out)
{
    const int b = blockIdx.x;
    const int lane = threadIdx.x;
    const float b21 = b21p[0], b22 = b22p[0];

    float a1[4], a2[4];
    float m1 = -1e30f, m2 = -1e30f;
    #pragma unroll
    for (int i = 0; i < 4; ++i) {
        int s = i * 64 + lane;
        float lw = logf(w[b * 256 + s]);
        a1[i] = plm[b * 256 + s] + b21 + lw;
        a2[i] = plv[b * 256 + s] + b22 + 2.f * lw;
        m1 = fmaxf(m1, a1[i]);
        m2 = fmaxf(m2, a2[i]);
    }
    #pragma unroll
    for (int m = 1; m < 64; m <<= 1) {
        m1 = fmaxf(m1, __shfl_xor(m1, m));
        m2 = fmaxf(m2, __shfl_xor(m2, m));
    }
    float s1 = 0.f, s2 = 0.f;
    #pragma unroll
    for (int i = 0; i < 4; ++i) {
        s1 += expf(a1[i] - m1);
        s2 += expf(a2[i] - m2);
    }
    #pragma unroll
    for (int m = 1; m < 64; m <<= 1) {
        s1 += __shfl_xor(s1, m);
        s2 += __shfl_xor(s2, m);
    }
    if (lane == 0) {
        float lm_agg = m1 + logf(s1);
        float lv_agg = m2 + logf(s2);
        float logl = logf(l[b]);
        out[b]       = logl - lm_agg;
        out[512 + b] = logl - 3.f * lm_agg - lv_agg;
    }
}

extern "C" void kernel_launch(void* const* d_in, const int* in_sizes, int n_in,
                              void* d_out, int out_size, void* d_ws, size_t ws_size,
                              hipStream_t stream) {
    const float* rho     = (const float*)d_in[0];
    const float* c       = (const float*)d_in[1];
    const float* w       = (const float*)d_in[2];
    const float* l       = (const float*)d_in[3];
    // d_in[4] = roads (unused by the reference)
    const int*   lon_idx = (const int*)d_in[5];
    const int*   lat_idx = (const int*)d_in[6];
    const float* f2W1    = (const float*)d_in[7];
    const float* f2b1    = (const float*)d_in[8];
    const float* f2W2    = (const float*)d_in[9];
    const float* f2b2    = (const float*)d_in[10];
    const float* fW1     = (const float*)d_in[11];
    const float* fb1     = (const float*)d_in[12];
    const float* fW21    = (const float*)d_in[13];
    const float* fb21    = (const float*)d_in[14];
    const float* fW22    = (const float*)d_in[15];
    const float* fb22    = (const float*)d_in[16];
    float* out = (float*)d_out;

    char* ws = (char*)d_ws;
    float*     cbias = (float*)(ws);               // 1048576 B
    short*     w1img = (short*)(ws + 1048576);     //  262144 B
    float*     plm   = (float*)(ws + 1310720);     //  524288 B
    float*     plv   = (float*)(ws + 1835008);     //  524288 B
    _Float16*  wvec  = (_Float16*)(ws + 2359296);  //   16384 B

    prep_all_kernel<<<784, 512, 0, stream>>>(c, lat_idx, lon_idx,
                                             f2W1, f2b1, f2W2, f2b2,
                                             fW1, fb1, fW21, fW22,
                                             w1img, wvec, cbias);
    fused_gemm_kernel<<<2048, 512, 0, stream>>>(rho, w1img, cbias, wvec,
                                                plm, plv);
    finalize_kernel<<<512, 64, 0, stream>>>(plm, plv, w, l, fb21, fb22, out);
}